// Round 6
// baseline (583.670 us; speedup 1.0000x reference)
//
#include <hip/hip_runtime.h>

typedef float v2f __attribute__((ext_vector_type(2)));

#define IS2 0.70710678118654752440f   // np.float32(1/sqrt(2))

__device__ __forceinline__ int refl(int i, int n) {
    if (i < 0) i = -1 - i;
    if (i >= n) i = 2 * n - 1 - i;
    return i;
}

__device__ __forceinline__ float smag(float re, float im) {
    return sqrtf(re * re + im * im + 1.0e-4f) - 0.01f;
}

// ---------------------------------------------------------------------------
// j1 tile: rowfilter(h0/h1) -> colfilter(h0/h1) -> q2c -> mag
// MODE 0: level-1 on x (N=512, CH=3): ll raw -> ll_out, mags -> p buffer
// MODE 1: level-2 on p (N=256, CH=18): mags -> Z groups 13+o2*6+o1 (NT),
//         avgpool2(ll) -> Z groups 1+o1 (NT).
// v6: tile narrowed 64x64 -> 32 rows x 64 cols. smem = 38x128 split-plane
// (lo at row*128+j, hi at row*128+64+j) overlaying the 38x72 input tile:
// 4864 floats = 19.5 KB -> 8 blocks/CU (32 waves, wave-cap occupancy; was
// 4 blocks at 35.8 KB). Everything else (b128 row pass, split-plane
// conflict-free col loads, pk-FMA, shfl_xor q2c) unchanged from v5.
// ---------------------------------------------------------------------------
template <int MODE, int N, int CH>
__device__ __forceinline__
void j1_tile(float* __restrict__ smem,
             const float* __restrict__ in,
             const float* __restrict__ h0,
             const float* __restrict__ h1,
             float* __restrict__ ll_out,
             float* __restrict__ mag_out,
             int img, int ty0, int tx0)
{
    const int b   = img / CH;
    const int chn = img % CH;
    const int tid = threadIdx.x;

    float* const sx = smem;   // 38*72 input tile (rows ty0-3.., cols tx0-4..)
    float* const s2 = smem;   // 38 rows x [lo:64 | hi:64] after row pass

    float f0[5], f1[7];
#pragma unroll
    for (int t = 0; t < 5; ++t) f0[t] = h0[t];
#pragma unroll
    for (int t = 0; t < 7; ++t) f1[t] = h1[t];

    const float* src = in + (size_t)img * N * N;

    // ---- load input tile: rows ty0-3..ty0+34, cols tx0-4..tx0+67 ----
    const bool interior = (ty0 >= 3) && (ty0 + 34 <= N - 1) &&
                          (tx0 >= 4) && (tx0 + 67 <= N - 1);
    if (interior) {
        const float* bp = src + (size_t)(ty0 - 3) * N + (tx0 - 4);
        for (int e = tid; e < 38 * 18; e += 256) {
            int rr = e / 18, g = e - rr * 18;
            *(float4*)&sx[rr * 72 + 4 * g] =
                *(const float4*)(bp + (size_t)rr * N + 4 * g);
        }
    } else {
        for (int e = tid; e < 38 * 72; e += 256) {
            int rr = e / 72, cc = e - rr * 72;
            int gr = refl(ty0 - 3 + rr, N);
            int gc = refl(tx0 - 4 + cc, N);
            sx[rr * 72 + cc] = src[(size_t)gr * N + gc];
        }
    }
    __syncthreads();

    // ---- row pass: 38 rows x 16 col-groups of 4; 3x b128 reads per group ----
    // output col jo=4g+u: lo taps sx cols jo+2..jo+6, hi taps jo+1..jo+7.
    float4 rLo[3], rHi[3];
#pragma unroll
    for (int k = 0; k < 3; ++k) {
        int e = tid + k * 256;
        if (e < 608) {
            int rr = e >> 4, g = e & 15;
            const float4* w4 = (const float4*)&sx[rr * 72 + 4 * g];
            float4 wa = w4[0], wb = w4[1], wc = w4[2];
            float win[12] = {wa.x, wa.y, wa.z, wa.w,
                             wb.x, wb.y, wb.z, wb.w,
                             wc.x, wc.y, wc.z, wc.w};
            float lo[4], hi[4];
#pragma unroll
            for (int u = 0; u < 4; ++u) {
                float l = 0.f, h = 0.f;
#pragma unroll
                for (int t = 0; t < 5; ++t) l += win[u + 2 + t] * f0[t];
#pragma unroll
                for (int t = 0; t < 7; ++t) h += win[u + 1 + t] * f1[t];
                lo[u] = l; hi[u] = h;
            }
            rLo[k] = make_float4(lo[0], lo[1], lo[2], lo[3]);
            rHi[k] = make_float4(hi[0], hi[1], hi[2], hi[3]);
        }
    }
    __syncthreads();   // all reads of sx complete
#pragma unroll
    for (int k = 0; k < 3; ++k) {
        int e = tid + k * 256;
        if (e < 608) {
            int rr = e >> 4, g = e & 15;
            *(float4*)&s2[rr * 128 + 4 * g]      = rLo[k];
            *(float4*)&s2[rr * 128 + 64 + 4 * g] = rHi[k];
        }
    }
    __syncthreads();

    // ---- col pass: one column x 8-row strip per thread, packed lo/hi ----
    const int j     = tid & 63;    // output column
    const int rg    = tid >> 6;    // row-group 0..3 -> rows rg*8 .. rg*8+7
    const int rbase = rg * 8;

    v2f w[14];
#pragma unroll
    for (int t = 0; t < 14; ++t) {
        const float* rp = &s2[(rbase + t) * 128 + j];
        w[t] = (v2f){rp[0], rp[64]};   // ds_read2_b32, bank = j mod 32
    }

    v2f f0d[5], f1d[7];
#pragma unroll
    for (int t = 0; t < 5; ++t) f0d[t] = (v2f){f0[t], f0[t]};
#pragma unroll
    for (int t = 0; t < 7; ++t) f1d[t] = (v2f){f1[t], f1[t]};

    const int Nh  = N >> 1;
    const int par = j & 1;
    const int qx  = (tx0 >> 1) + (j >> 1);
    const int qy0 = (ty0 >> 1) + rg * 4;
    const int oLH = par ? 5 : 0;
    const int oHH = par ? 4 : 1;
    const int oHL = par ? 3 : 2;

    float* lcol = nullptr;
    float* pLH = nullptr; float* pHH = nullptr; float* pHL = nullptr;
    float* zLH = nullptr; float* zHH = nullptr; float* zHL = nullptr;
    float* zPL = nullptr;
    if (MODE == 0) {
        lcol = ll_out + (size_t)img * N * N + (size_t)(ty0 + rbase) * N + tx0 + j;
        const size_t planeSz = (size_t)Nh * Nh;
        const size_t qoff = (size_t)qy0 * Nh + qx;
        pLH = mag_out + ((size_t)(b * 6 + oLH) * CH + chn) * planeSz + qoff;
        pHH = mag_out + ((size_t)(b * 6 + oHH) * CH + chn) * planeSz + qoff;
        pHL = mag_out + ((size_t)(b * 6 + oHL) * CH + chn) * planeSz + qoff;
    } else {
        const int o1 = chn / 3, c3 = chn % 3;
        float* zBase = mag_out + (size_t)b * 147 * 16384 + (size_t)qy0 * 128 + qx;
        zLH = zBase + (size_t)((13 + oLH * 6 + o1) * 3 + c3) * 16384;
        zHH = zBase + (size_t)((13 + oHH * 6 + o1) * 3 + c3) * 16384;
        zHL = zBase + (size_t)((13 + oHL * 6 + o1) * 3 + c3) * 16384;
        zPL = zBase + (size_t)((1 + o1) * 3 + c3) * 16384;
    }

#pragma unroll
    for (int ii = 0; ii < 4; ++ii) {
        const int i0 = 2 * ii, i1 = 2 * ii + 1;
        v2f A0 = {0.f, 0.f}, A1 = {0.f, 0.f};   // (ll, hl) rows i0, i1
        v2f C0 = {0.f, 0.f}, C1 = {0.f, 0.f};   // (lh, hh) rows i0, i1
#pragma unroll
        for (int t = 0; t < 5; ++t) {
            A0 += w[i0 + 1 + t] * f0d[t];
            A1 += w[i1 + 1 + t] * f0d[t];
        }
#pragma unroll
        for (int t = 0; t < 7; ++t) {
            C0 += w[i0 + t] * f1d[t];
            C1 += w[i1 + t] * f1d[t];
        }
        float ll0 = A0.x, hl0 = A0.y, ll1 = A1.x, hl1 = A1.y;
        float lh0 = C0.x, hh0 = C0.y, lh1 = C1.x, hh1 = C1.y;

        // q2c across the lane pair (even: a,c | odd: b,d); smag symmetric.
        float lhT = __shfl_xor(lh0, 1), lhB = __shfl_xor(lh1, 1);
        float hhT = __shfl_xor(hh0, 1), hhB = __shfl_xor(hh1, 1);
        float hlT = __shfl_xor(hl0, 1), hlB = __shfl_xor(hl1, 1);
        float mLH = smag(IS2 * (lh0 - lhB), IS2 * (lhT + lh1));
        float mHH = smag(IS2 * (hh0 - hhB), IS2 * (hhT + hh1));
        float mHL = smag(IS2 * (hl0 - hlB), IS2 * (hlT + hl1));

        if (MODE == 0) {
            lcol[(size_t)i0 * N] = ll0;
            lcol[(size_t)i1 * N] = ll1;
            pLH[ii * Nh] = mLH;
            pHH[ii * Nh] = mHH;
            pHL[ii * Nh] = mHL;
        } else {
            __builtin_nontemporal_store(mLH, zLH + ii * 128);
            __builtin_nontemporal_store(mHH, zHH + ii * 128);
            __builtin_nontemporal_store(mHL, zHL + ii * 128);
            float llT = __shfl_xor(ll0, 1), llB = __shfl_xor(ll1, 1);
            if (par == 0) {
                __builtin_nontemporal_store(
                    0.25f * (ll0 + ll1 + llT + llB), zPL + ii * 128);
            }
        }
    }
}

// ---------------------------------------------------------------------------
// j2 tile: rowdfilt -> coldfilt -> q2c -> mag -> Z[s1_j2] (NT), avgpool -> Z[s0] (NT)
// v6: tile narrowed 32x32 -> 16 rows x 32 cols (256-space); ll tile 48x80.
// smem = max(48*84 input, 48*64 split-plane) = 4032 floats = 16.1 KB.
// Each thread produces ONE Z-row (g 0..7 -> Z-row (r0>>1)+g from local
// filtered rows 4g..4g+19). Broadcast-pair b64 row pass + pk-FMA unchanged.
// ---------------------------------------------------------------------------
__device__ __forceinline__
void j2_tile(float* __restrict__ smem,
             const float* __restrict__ ll,
             const float* __restrict__ h0a, const float* __restrict__ h0b,
             const float* __restrict__ h1a, const float* __restrict__ h1b,
             float* __restrict__ Z, int img, int r0, int c0)
{
    const int b = img / 3, c = img % 3;
    const int tid = threadIdx.x;

    float* const sx = smem;   // 48*84 input tile
    float* const s2 = smem;   // 48 rows x [lo:32 | hi:32] after row pass

    float fa0[10], fb0[10], fa1[10], fb1[10];
#pragma unroll
    for (int t = 0; t < 10; ++t) {
        fa0[t] = h0a[t]; fb0[t] = h0b[t];
        fa1[t] = h1a[t]; fb1[t] = h1b[t];
    }

    const float* src = ll + (size_t)img * 512 * 512;
    const int gy0 = 2 * r0 - 8, gx0 = 2 * c0 - 8;

    // ---- load 48x80 x-tile (rows gy0..gy0+47, cols gx0..gx0+79), reflect ----
    const bool interior = (gy0 >= 0) && (gy0 + 47 <= 511) &&
                          (gx0 >= 0) && (gx0 + 79 <= 511);
    if (interior) {
        const float* bp = src + (size_t)gy0 * 512 + gx0;
        for (int e = tid; e < 48 * 20; e += 256) {
            int rr = e / 20, g = e - rr * 20;
            *(float4*)&sx[rr * 84 + 4 * g] =
                *(const float4*)(bp + (size_t)rr * 512 + 4 * g);
        }
    } else {
        for (int e = tid; e < 48 * 80; e += 256) {
            int rr = e / 80, cc = e - rr * 80;
            int gr = refl(gy0 + rr, 512);
            int gc = refl(gx0 + cc, 512);
            sx[rr * 84 + cc] = src[(size_t)gr * 512 + gc];
        }
    }
    __syncthreads();

    // ---- row pass (rowdfilt), packed: acc = sum pair(row, base+2t) * fp[t]
    // even thread (odd=0): acc = (lo, hi); odd thread: acc = (hi, lo).
    const int jj  = tid & 31;
    const int odd = jj & 1;
    const int base = 2 * (jj & ~1);
    v2f fp[10];
#pragma unroll
    for (int t = 0; t < 10; ++t) {
        fp[t] = odd ? (v2f){fb1[t], fa0[t]} : (v2f){fb0[t], fa1[t]};
    }
    v2f racc[6];
#pragma unroll
    for (int k = 0; k < 6; ++k) {
        int rr = (tid >> 5) + 8 * k;
        const float* row = &sx[rr * 84 + base];
        v2f acc = {0.f, 0.f};
#pragma unroll
        for (int t = 0; t < 10; ++t) {
            acc += (*(const v2f*)&row[2 * t]) * fp[t];
        }
        racc[k] = odd ? (v2f){acc.y, acc.x} : acc;   // (lo, hi)
    }
    __syncthreads();   // all reads of sx complete
#pragma unroll
    for (int k = 0; k < 6; ++k) {
        int rr = (tid >> 5) + 8 * k;
        s2[rr * 64 + jj]      = racc[k].x;   // lo plane, bank = jj (free)
        s2[rr * 64 + 32 + jj] = racc[k].y;   // hi plane (ds_write2_b32 pair)
    }
    __syncthreads();

    // ---- col pass: thread = (col j 0..31, group g 0..7) -> ONE Z-row ----
    const int j = tid & 31;
    const int g = tid >> 5;

    v2f w[20];
#pragma unroll
    for (int t = 0; t < 20; ++t) {
        const float* rp = &s2[(4 * g + t) * 64 + j];
        w[t] = (v2f){rp[0], rp[32]};   // ds_read2_b32, bank = j mod 32
    }

    const int dj  = j & 1;
    const int qx  = (c0 >> 1) + (j >> 1);
    const int qy  = (r0 >> 1) + g;
    const int oLH = dj ? 5 : 0;
    const int oHH = dj ? 4 : 1;
    const int oHL = dj ? 3 : 2;

    float* Zb = Z + (size_t)b * 147 * 16384 + (size_t)qy * 128 + qx;
    float* zLH = Zb + (size_t)((7 + oLH) * 3 + c) * 16384;
    float* zHH = Zb + (size_t)((7 + oHH) * 3 + c) * 16384;
    float* zHL = Zb + (size_t)((7 + oHL) * 3 + c) * 16384;
    float* zPL = Zb + (size_t)c * 16384;

    float vll0 = 0.f, vll1 = 0.f, vlh0 = 0.f, vlh1 = 0.f;
    float vhl0 = 0.f, vhl1 = 0.f, vhh0 = 0.f, vhh1 = 0.f;
#pragma unroll
    for (int t = 0; t < 10; ++t) {
        v2f p0 = w[2 * t];       // (lo, hi) local row 4g+2t
        v2f p1 = w[2 * t + 1];   // (lo, hi) local row 4g+2t+1
        vll0 += p0.x * fb0[t];
        vll1 += p1.x * fa0[t];
        vlh0 += p1.x * fa1[t];
        vlh1 += p0.x * fb1[t];
        vhl0 += p0.y * fb0[t];
        vhl1 += p1.y * fa0[t];
        vhh0 += p1.y * fa1[t];
        vhh1 += p0.y * fb1[t];
    }

    // q2c: even lane holds (a,c) of the quad, odd holds (b,d)
    float lhT = __shfl_xor(vlh0, 1), lhB = __shfl_xor(vlh1, 1);
    float hhT = __shfl_xor(vhh0, 1), hhB = __shfl_xor(vhh1, 1);
    float hlT = __shfl_xor(vhl0, 1), hlB = __shfl_xor(vhl1, 1);
    float mLH = smag(IS2 * (vlh0 - lhB), IS2 * (lhT + vlh1));
    float mHH = smag(IS2 * (vhh0 - hhB), IS2 * (hhT + vhh1));
    float mHL = smag(IS2 * (vhl0 - hlB), IS2 * (hlT + vhl1));

    __builtin_nontemporal_store(mLH, zLH);
    __builtin_nontemporal_store(mHH, zHH);
    __builtin_nontemporal_store(mHL, zHL);

    float llT = __shfl_xor(vll0, 1), llB = __shfl_xor(vll1, 1);
    if (dj == 0) {
        __builtin_nontemporal_store(
            0.25f * (vll0 + vll1 + llT + llB), zPL);
    }
}

// ---------------------------------------------------------------------------
// Kernel A: level-1 j1 on x -> ll + p.  Tiles 32 rows x 64 cols.
// ---------------------------------------------------------------------------
__global__ __launch_bounds__(256, 8)
void k_j1_l1(const float* __restrict__ x,
             const float* __restrict__ h0o, const float* __restrict__ h1o,
             float* __restrict__ ll, float* __restrict__ p)
{
    __shared__ __align__(16) float smem[4864];
    j1_tile<0, 512, 3>(smem, x, h0o, h1o, ll, p,
                       blockIdx.z, blockIdx.y * 32, blockIdx.x * 64);
}

// ---------------------------------------------------------------------------
// Kernel B: fused phase 2+3 (independent consumers of kernel A's outputs).
// blocks [0,18432): j1<1> tiles (32x64 on 256x256, 32 tiles/img x 576);
// [18432,30720): j2 tiles (16x32 in 256-space, 128 tiles/img x 96).
// ---------------------------------------------------------------------------
__global__ __launch_bounds__(256, 8)
void k_p23(const float* __restrict__ ll, const float* __restrict__ p,
           const float* __restrict__ h0o, const float* __restrict__ h1o,
           const float* __restrict__ h0a, const float* __restrict__ h0b,
           const float* __restrict__ h1a, const float* __restrict__ h1b,
           float* __restrict__ Z)
{
    __shared__ __align__(16) float smem[4864];
    const int B = blockIdx.x;
    if (B < 18432) {
        const int img = B >> 5, rem = B & 31;
        j1_tile<1, 256, 18>(smem, p, h0o, h1o, nullptr, Z,
                            img, (rem >> 2) * 32, (rem & 3) * 64);
    } else {
        const int T = B - 18432;
        const int img = T >> 7, rem = T & 127;
        j2_tile(smem, ll, h0a, h0b, h1a, h1b, Z,
                img, (rem >> 3) * 16, (rem & 7) * 32);
    }
}

extern "C" void kernel_launch(void* const* d_in, const int* in_sizes, int n_in,
                              void* d_out, int out_size, void* d_ws, size_t ws_size,
                              hipStream_t stream)
{
    const float* x   = (const float*)d_in[0];
    const float* h0o = (const float*)d_in[1];
    const float* h1o = (const float*)d_in[2];
    const float* h0a = (const float*)d_in[3];
    const float* h0b = (const float*)d_in[4];
    const float* h1a = (const float*)d_in[5];
    const float* h1b = (const float*)d_in[6];
    float* Z = (float*)d_out;

    float* ws_ll = (float*)d_ws;                          // (32,3,512,512)
    float* ws_p  = ws_ll + (size_t)32 * 3 * 512 * 512;    // (32,18,256,256)

    dim3 blk(256);
    // phase 1: level-1 j1 on x -> ll + p
    k_j1_l1<<<dim3(8, 16, 96), blk, 0, stream>>>(x, h0o, h1o, ws_ll, ws_p);
    // phases 2+3 fused: j1<1> on p -> Z[s1_j1,s2]; j2 on ll -> Z[s0,s1_j2]
    k_p23<<<dim3(30720), blk, 0, stream>>>(ws_ll, ws_p, h0o, h1o,
                                           h0a, h0b, h1a, h1b, Z);
}